// Round 3
// baseline (2023.827 us; speedup 1.0000x reference)
//
#include <hip/hip_runtime.h>

#define HID 256

typedef __attribute__((ext_vector_type(8))) short short8;
typedef __attribute__((ext_vector_type(4))) float floatx4;

// round-to-nearest-even fp32 -> bf16 (bits in a short)
__device__ __forceinline__ short f2bf(float f) {
  unsigned u = __float_as_uint(f);
  unsigned r = (u + 0x7fffu + ((u >> 16) & 1u)) >> 16;
  return (short)r;
}

// tanh(v) = 1 - 2/(exp(2v)+1); exact limits at +-inf of exp
__device__ __forceinline__ float tanh_fast(float v) {
  float e = __expf(2.0f * v);
  return 1.0f - 2.0f * __builtin_amdgcn_rcpf(e + 1.0f);
}

// ---------------------------------------------------------------------------
// Kernel 0: seg[g] = lower_bound(batch, g) for g in [0, G]. batch sorted.
// Amortizes the binary search once instead of per-wave-per-graph.
// ---------------------------------------------------------------------------
__global__ __launch_bounds__(256)
void seg_kernel(const int* __restrict__ batch, int* __restrict__ seg,
                int N, int G) {
  int g = blockIdx.x * 256 + threadIdx.x;
  if (g > G) return;
  int lo = 0, hi = N;
  while (lo < hi) {
    int mid = (lo + hi) >> 1;
    if (batch[mid] < g) lo = mid + 1; else hi = mid;
  }
  seg[g] = lo;
}

// ---------------------------------------------------------------------------
// Fused kernel: per graph, single pass over its nodes.
//   gate_i = tanh(x_i W1 + b1) W2          (b2 dropped: softmax-shift-invariant)
//   out[g] = sum_i exp(gate_i) x_i / (sum_i exp(gate_i) + 1e-16)
// No max subtraction needed: |gate| <= sum|W2| + |b2| <= ~11.4 (tanh bounded),
// so exp() is far from fp32 overflow/underflow; result is mathematically
// identical to the max-subtracted reference.
//
// Structure: 512 persistent blocks (2/CU, W1 bf16 in 64 KB LDS staged once).
// One graph per wave. Per 16-row tile of the graph's segment:
//   - lane (r16,quad) loads row r16's columns {8q+32s..+7} (16 float4, fp32,
//     kept live for the weighted accumulate)
//   - 16x16x32 bf16 MFMA as in the verified gate kernel (same frag layouts)
//   - layer 2 + butterfly reduce -> gates; shfl-redistribute so each lane
//     owns e = exp(gate(row r16)); accumulate pacc[c] += e * x[row][c]
// Graph end: butterfly-sum pacc/ssum over the 16 r16 lanes, scale, store
// with STATIC pacc indexing (predicated per-s stores) to avoid scratch.
// ---------------------------------------------------------------------------
__global__ __launch_bounds__(256, 2)
void fused_kernel(const float* __restrict__ x, const float* __restrict__ W1,
                  const float* __restrict__ B1, const float* __restrict__ W2,
                  const int* __restrict__ seg, float* __restrict__ out, int G) {
  __shared__ __align__(16) short sW1[32768];  // 64 KB, W1 in bf16 B-frag order

  const int tid = threadIdx.x;

  // stage W1 fp32 [k=256][n=128] -> swizzled bf16 fragment layout (verified)
  for (int idx = tid; idx < 32768; idx += 256) {
    int k = idx >> 7, n = idx & 127;
    int lane_s = (n & 15) | (((k >> 3) & 3) << 4);         // frag lane
    int pos = (((n >> 4) * 8 + (k >> 5)) * 64 + lane_s) * 8 + (k & 7);
    sW1[pos] = f2bf(W1[idx]);
  }
  __syncthreads();

  const int lane = tid & 63;
  const int quad = lane >> 4;   // 0..3
  const int r16  = lane & 15;

  // per-lane layer-2 constants: n = nt*16 + r16
  float b1v[8], w2v[8];
#pragma unroll
  for (int nt = 0; nt < 8; ++nt) {
    b1v[nt] = B1[nt * 16 + r16];
    w2v[nt] = W2[nt * 16 + r16];
  }

  const short8* bfr = (const short8*)sW1;
  const int gwave  = blockIdx.x * 4 + (tid >> 6);
  const int nWaves = gridDim.x * 4;

  // redistribution: gate for relative row r16 lives as p[r16&3] in quad (r16>>2)
  const int srcl = ((r16 >> 2) << 4) | r16;
  const int rsel = r16 & 3;

  int start = (gwave < G) ? seg[gwave] : 0;
  int end   = (gwave < G) ? seg[gwave + 1] : 0;

  for (int g = gwave; g < G; g += nWaves) {
    floatx4 pacc[16];
#pragma unroll
    for (int s = 0; s < 16; ++s) pacc[s] = (floatx4){0.f, 0.f, 0.f, 0.f};
    float ssum = 0.f;

    const int curS = start, curE = end;

    for (int t0 = curS; t0 < curE; t0 += 16) {
      int row = t0 + r16;
      const bool valid = row < curE;
      if (!valid) row = curE - 1;  // duplicate last row (cached); masked via e=0

      const float4* xr = (const float4*)(x + (size_t)row * HID) + quad * 2;
      float4 xa[16];
#pragma unroll
      for (int s = 0; s < 8; ++s) {
        xa[2 * s]     = xr[s * 8];
        xa[2 * s + 1] = xr[s * 8 + 1];
      }

      floatx4 acc[8];
#pragma unroll
      for (int nt = 0; nt < 8; ++nt) acc[nt] = (floatx4){0.f, 0.f, 0.f, 0.f};

#pragma unroll
      for (int s = 0; s < 8; ++s) {
        float4 u = xa[2 * s], v = xa[2 * s + 1];
        short8 a = {f2bf(u.x), f2bf(u.y), f2bf(u.z), f2bf(u.w),
                    f2bf(v.x), f2bf(v.y), f2bf(v.z), f2bf(v.w)};
#pragma unroll
        for (int nt = 0; nt < 8; ++nt) {
          short8 bf = bfr[(nt * 8 + s) * 64 + lane];
          acc[nt] = __builtin_amdgcn_mfma_f32_16x16x32_bf16(a, bf, acc[nt], 0, 0, 0);
        }
      }

      // layer 2: p[r] = sum_n tanh(h + b1[n]) * W2[n], n split across 16 lanes
      float p0 = 0.f, p1 = 0.f, p2 = 0.f, p3 = 0.f;
#pragma unroll
      for (int nt = 0; nt < 8; ++nt) {
        float bb = b1v[nt], ww = w2v[nt];
        p0 = fmaf(tanh_fast(acc[nt][0] + bb), ww, p0);
        p1 = fmaf(tanh_fast(acc[nt][1] + bb), ww, p1);
        p2 = fmaf(tanh_fast(acc[nt][2] + bb), ww, p2);
        p3 = fmaf(tanh_fast(acc[nt][3] + bb), ww, p3);
      }
      // butterfly-sum across the 16 lanes of each quad group -> all lanes hold
      // p_j = gate(row t0 + quad*4 + j)
#pragma unroll
      for (int off = 1; off < 16; off <<= 1) {
        p0 += __shfl_xor(p0, off, 64);
        p1 += __shfl_xor(p1, off, 64);
        p2 += __shfl_xor(p2, off, 64);
        p3 += __shfl_xor(p3, off, 64);
      }
      // fetch this lane's own-row gate (relative row r16)
      float g0 = __shfl(p0, srcl, 64);
      float g1 = __shfl(p1, srcl, 64);
      float g2 = __shfl(p2, srcl, 64);
      float g3 = __shfl(p3, srcl, 64);
      float gown = (rsel == 0) ? g0 : (rsel == 1) ? g1 : (rsel == 2) ? g2 : g3;

      float e = valid ? __expf(gown) : 0.f;
      ssum += e;

      // weighted accumulate: lane's 64 columns of row r16
#pragma unroll
      for (int s = 0; s < 16; ++s) {
        pacc[s][0] = fmaf(e, xa[s].x, pacc[s][0]);
        pacc[s][1] = fmaf(e, xa[s].y, pacc[s][1]);
        pacc[s][2] = fmaf(e, xa[s].z, pacc[s][2]);
        pacc[s][3] = fmaf(e, xa[s].w, pacc[s][3]);
      }
    }

    // prefetch next graph's bounds before the epilogue reduce hides the latency
    const int gn = g + nWaves;
    if (gn < G) {
      start = seg[gn];
      end   = seg[gn + 1];
    }

    // reduce over the 16 r16 lanes (each column lives in exactly one quad)
#pragma unroll
    for (int off = 1; off < 16; off <<= 1) {
      ssum += __shfl_xor(ssum, off, 64);
#pragma unroll
      for (int s = 0; s < 16; ++s) {
        pacc[s][0] += __shfl_xor(pacc[s][0], off, 64);
        pacc[s][1] += __shfl_xor(pacc[s][1], off, 64);
        pacc[s][2] += __shfl_xor(pacc[s][2], off, 64);
        pacc[s][3] += __shfl_xor(pacc[s][3], off, 64);
      }
    }

    const float inv = 1.0f / (ssum + 1e-16f);
    float* op = out + (size_t)g * HID + quad * 8;
    // static-indexed predicated stores: pacc[2u],pacc[2u+1] -> cols 32u + 8q
#pragma unroll
    for (int s = 0; s < 16; s += 2) {
      if (r16 == (s >> 1)) {
        float4 o0 = {pacc[s][0] * inv, pacc[s][1] * inv,
                     pacc[s][2] * inv, pacc[s][3] * inv};
        float4 o1 = {pacc[s + 1][0] * inv, pacc[s + 1][1] * inv,
                     pacc[s + 1][2] * inv, pacc[s + 1][3] * inv};
        *(float4*)(op + s * 16)     = o0;
        *(float4*)(op + s * 16 + 4) = o1;
      }
    }
  }
}

extern "C" void kernel_launch(void* const* d_in, const int* in_sizes, int n_in,
                              void* d_out, int out_size, void* d_ws, size_t ws_size,
                              hipStream_t stream) {
  const float* x   = (const float*)d_in[0];
  const float* W1  = (const float*)d_in[1];
  const float* b1  = (const float*)d_in[2];
  const float* W2  = (const float*)d_in[3];
  const int*  batch = (const int*)d_in[5];
  float* out = (float*)d_out;
  int*   seg = (int*)d_ws;             // (G+1) ints of workspace

  const int N = in_sizes[0] / HID;     // 1,000,000
  const int G = out_size / HID;        // 8192

  seg_kernel<<<(G + 1 + 255) / 256, 256, 0, stream>>>(batch, seg, N, G);
  fused_kernel<<<512, 256, 0, stream>>>(x, W1, b1, W2, seg, out, G);
}